// Round 14
// baseline (133.960 us; speedup 1.0000x reference)
//
#include <hip/hip_runtime.h>
#include <stdint.h>

#define RT    2336          // routes
#define RLDS  1568          // routes resident in LDS (bf16 quads, 8 B/slice)
#define SCUT  12            // phase-A steps 0..SCUT-1 -> LDS, SCUT..17 -> regs
#define NRS   6             // bf16-packed register residue slots (18 - SCUT)
#define NSL   13            // pass-2/3 LDS slice iterations (ceil(RLDS*4/512))
#define NTH   512
#define NBLK  2048          // one block per (b,k), XCD-pair swizzled
#define BATCH 1024
#define SH1   32.0f         // fixed softmax exponent shift, pass 2 (ratio cancels)
#define SH2   64.0f         // fixed softmax exponent shift, pass 3

typedef float v2f __attribute__((ext_vector_type(2)));

__device__ __forceinline__ float blo(uint32_t v){ union {uint32_t u; float f;} x; x.u = v << 16;        return x.f; }
__device__ __forceinline__ float bhi(uint32_t v){ union {uint32_t u; float f;} x; x.u = v & 0xffff0000u; return x.f; }

// 2x f32 -> packed bf16, ONE instruction (RNE; HW-verified R13: absmax
// unchanged vs manual f2b_pack). The manual pack cost ~10 VALU ops.
__device__ __forceinline__ uint32_t cvtpk_bf16(float a, float b){
  uint32_t r;
  asm("v_cvt_pk_bf16_f32 %0, %1, %2" : "=v"(r) : "v"(a), "v"(b));
  return r;
}

// Packed 2x f32 VOP3P ops: exact f32 math, half the issue count (R13-verified).
__device__ __forceinline__ v2f pk_fma(v2f a, v2f b, v2f c){
  v2f d; asm("v_pk_fma_f32 %0, %1, %2, %3" : "=v"(d) : "v"(a), "v"(b), "v"(c));
  return d;
}
__device__ __forceinline__ v2f pk_mul(v2f a, v2f b){
  v2f d; asm("v_pk_mul_f32 %0, %1, %2" : "=v"(d) : "v"(a), "v"(b));
  return d;
}
__device__ __forceinline__ v2f pk_add(v2f a, v2f b){
  v2f d; asm("v_pk_add_f32 %0, %1, %2" : "=v"(d) : "v"(a), "v"(b));
  return d;
}

// Quad (4-lane) all-reduce sum via DPP quad_perm (VALU pipe, no LDS).
__device__ __forceinline__ float qsum4(float d){
  d += __int_as_float(__builtin_amdgcn_update_dpp(
         0, __float_as_int(d), 0xB1, 0xF, 0xF, true));
  d += __int_as_float(__builtin_amdgcn_update_dpp(
         0, __float_as_int(d), 0x4E, 0xF, 0xF, true));
  return d;
}

// Quad-layout block merge: each lane holds (l, a[4]) for its o-quad qo = tid&3.
// Reduces over lanes with equal tid%4; final stage parallel over 16 lanes.
__device__ __forceinline__ void merge_quad(float4 a, float l, int tid,
                                           float (*red)[4][5], float* vbuf,
                                           bool last, float* out_cls){
  #pragma unroll
  for (int off = 32; off >= 4; off >>= 1){
    a.x += __shfl_down(a.x, off); a.y += __shfl_down(a.y, off);
    a.z += __shfl_down(a.z, off); a.w += __shfl_down(a.w, off);
    l   += __shfl_down(l,   off);
  }
  const int lane = tid & 63, wid = tid >> 6;
  if (lane < 4){
    red[wid][lane][0] = l;
    red[wid][lane][1] = a.x; red[wid][lane][2] = a.y;
    red[wid][lane][3] = a.z; red[wid][lane][4] = a.w;
  }
  __syncthreads();
  if (tid < 16){
    const int q = tid >> 2, j = tid & 3;   // lane owns output o = 4q + j
    float S = 0.f, partL = 0.f;
    #pragma unroll
    for (int w = 0; w < 8; ++w){
      S     += red[w][q][1 + j];
      partL += red[w][j][0];               // route-class j partial count
    }
    partL += __shfl_xor(partL, 1);
    partL += __shfl_xor(partL, 2);
    float L   = partL * 0.25f;
    float inv = 1.f / L;
    float Sn  = S * inv;                   // s = acc / L
    float nrm = Sn * Sn;                   // squared norm over 16 lanes
    nrm += __shfl_xor(nrm, 1);
    nrm += __shfl_xor(nrm, 2);
    nrm += __shfl_xor(nrm, 4);
    nrm += __shfl_xor(nrm, 8);
    if (last){
      if (tid == 0) *out_cls = nrm / (1.f + nrm);   // ||squash(s)|| = n/(1+n)
    } else {
      float f = sqrtf(nrm) / (1.f + nrm);           // squash scale on s
      vbuf[tid] = Sn * f;
    }
  }
  __syncthreads();
}

// Synthesis: R9 geometry (single batch/block, VGPR<=64 -> the occupancy knee's
// good side: occ 37-40% vs 20% at VGPR>64 [session R3/R9 vs R7/R10/R12/R13])
// + R13 instruction diet (cvt_pk, pk_fma, const route counts; -25% VALU issue,
// and fewer regs: uint2 residue 12 vs fp32 24 -> should kill R9's mild spill).
// launch_bounds arg=4 -> VGPR cap 64 (session model cap=512/(2*arg), verified).
__global__ void __launch_bounds__(NTH, 4)
caps_route(const float* __restrict__ U, const float* __restrict__ W,
           float* __restrict__ Out){
  __shared__ uint2 uj[RLDS * 4];      // slice idx = route*4 + qo : bf16x4
  __shared__ float red[8][4][5];
  __shared__ float vbuf[16];

  const int tid = threadIdx.x;
  const int qo  = tid & 3;            // my o-quad: o = 4*qo .. 4*qo+3

  // XCD-pair swizzle: k=0/1 of one batch adjacent on the same XCD -> u[b]
  // L2 reuse; W_k panels (1.2 MB total) stay L2-resident.
  const int c  = blockIdx.x & 7;
  const int jj = blockIdx.x >> 3;
  const int k  = jj & 1;
  const int b  = (c << 7) | (jj >> 1);

  const float* Ub = U + (size_t)b * (RT * 4);
  const float* Wk = W + (size_t)k * ((size_t)RT * 64) + qo * 4;

  uint2  ur[NRS];                     // bf16-packed residue (routes 1568..2335)
  float  vc0, vc1, vc2, vc3;          // my quad of v (accumulates v0+v1)

  // uji quad for route r via packed f32 ops: 8 pk (mul+fma) vs 16 scalar.
  auto build_rq = [&](int route, v2f& p01, v2f& p23){
    float4 u4 = *(const float4*)(Ub + (size_t)route * 4);
    const float* wr = Wk + (size_t)route * 64;
    float4 w0 = *(const float4*)(wr);
    float4 w1 = *(const float4*)(wr + 16);
    float4 w2 = *(const float4*)(wr + 32);
    float4 w3 = *(const float4*)(wr + 48);
    v2f s0 = {u4.x,u4.x}, s1 = {u4.y,u4.y}, s2 = {u4.z,u4.z}, s3 = {u4.w,u4.w};
    p01 = pk_mul(s0, (v2f){w0.x,w0.y});      p23 = pk_mul(s0, (v2f){w0.z,w0.w});
    p01 = pk_fma(s1, (v2f){w1.x,w1.y}, p01); p23 = pk_fma(s1, (v2f){w1.z,w1.w}, p23);
    p01 = pk_fma(s2, (v2f){w2.x,w2.y}, p01); p23 = pk_fma(s2, (v2f){w2.z,w2.w}, p23);
    p01 = pk_fma(s3, (v2f){w3.x,w3.y}, p01); p23 = pk_fma(s3, (v2f){w3.z,w3.w}, p23);
  };

  // ---------------- Phase A: build u_ji; fused pass 1 (uniform weights) ----
  v2f acc01 = {0.f,0.f}, acc23 = {0.f,0.f};

  if (tid < 128){                     // pre-step: routes 0..31
    int route = tid >> 2;
    v2f p01, p23; build_rq(route, p01, p23);
    acc01 = pk_add(acc01, p01); acc23 = pk_add(acc23, p23);
    uj[route*4 + qo] = make_uint2(cvtpk_bf16(p01.x, p01.y), cvtpk_bf16(p23.x, p23.y));
  }
  #pragma unroll 3
  for (int s = 0; s < SCUT; ++s){     // LDS routes: 32 + 128*s + tid/4
    int route = 32 + s*128 + (tid >> 2);
    v2f p01, p23; build_rq(route, p01, p23);
    acc01 = pk_add(acc01, p01); acc23 = pk_add(acc23, p23);
    uj[route*4 + qo] = make_uint2(cvtpk_bf16(p01.x, p01.y), cvtpk_bf16(p23.x, p23.y));
  }
  #pragma unroll
  for (int slot = 0; slot < NRS; ++slot){   // register routes, static slot
    int route = 32 + (SCUT + slot)*128 + (tid >> 2);
    v2f p01, p23; build_rq(route, p01, p23);
    acc01 = pk_add(acc01, p01); acc23 = pk_add(acc23, p23);
    ur[slot] = make_uint2(cvtpk_bf16(p01.x, p01.y), cvtpk_bf16(p23.x, p23.y));
  }
  // route count is compile-time: tid<128 handles 1 extra (pre-step) route.
  // class-total check: 32*19 + 96*18 = 2336 = RT per tid%4 class.
  float l = (tid < 128) ? 19.f : 18.f;
  merge_quad(make_float4(acc01.x, acc01.y, acc23.x, acc23.y), l,
             tid, red, vbuf, false, nullptr);                 // v0
  vc0 = vbuf[4*qo]; vc1 = vbuf[4*qo+1]; vc2 = vbuf[4*qo+2]; vc3 = vbuf[4*qo+3];

  // ---------------- Passes 2,3 (pass 3 uses vc = v0+v1; b starts at 0) ----
  for (int ps = 0; ps < 2; ++ps){
    const float SH = ps ? SH2 : SH1;
    float4 acc = make_float4(0.f,0.f,0.f,0.f);
    float lp = 0.f;
    #pragma unroll
    for (int s = 0; s < NSL; ++s){    // LDS slices, idx = tid + 512*s
      int idx = tid + (s << 9);
      bool act = (idx < RLDS * 4);    // only s==NSL-1 partial (tid<128)
      float uf0=0.f, uf1=0.f, uf2=0.f, uf3=0.f, d = 0.f;
      if (act){
        uint2 q2 = uj[idx];
        uf0 = blo(q2.x); uf1 = bhi(q2.x); uf2 = blo(q2.y); uf3 = bhi(q2.y);
        d = fmaf(uf0, vc0, fmaf(uf1, vc1, fmaf(uf2, vc2, uf3 * vc3)));
      }
      d = qsum4(d);                   // full route dot to all 4 lanes (DPP)
      if (act){
        float e = __expf(d - SH);
        lp += e;
        acc.x = fmaf(e, uf0, acc.x); acc.y = fmaf(e, uf1, acc.y);
        acc.z = fmaf(e, uf2, acc.z); acc.w = fmaf(e, uf3, acc.w);
      }
    }
    #pragma unroll
    for (int slot = 0; slot < NRS; ++slot){           // residue slices
      uint2 q2 = ur[slot];
      float uf0 = blo(q2.x), uf1 = bhi(q2.x), uf2 = blo(q2.y), uf3 = bhi(q2.y);
      float d = fmaf(uf0, vc0, fmaf(uf1, vc1, fmaf(uf2, vc2, uf3 * vc3)));
      d = qsum4(d);
      float e = __expf(d - SH);
      lp += e;
      acc.x = fmaf(e, uf0, acc.x); acc.y = fmaf(e, uf1, acc.y);
      acc.z = fmaf(e, uf2, acc.z); acc.w = fmaf(e, uf3, acc.w);
    }
    merge_quad(acc, lp, tid, red, vbuf, ps == 1, Out + ((b << 1) | k));
    if (ps == 0){                     // b2 = uji.(v0+v1): accumulate v
      vc0 += vbuf[4*qo]; vc1 += vbuf[4*qo+1];
      vc2 += vbuf[4*qo+2]; vc3 += vbuf[4*qo+3];
    }
  }
}

// In-place 2-way softmax over k: Out[b,0..1] fp32
__global__ void caps_softmax(float* __restrict__ Out){
  int b = blockIdx.x * blockDim.x + threadIdx.x;
  if (b < BATCH){
    float2* p = (float2*)Out;
    float2 c = p[b];
    float m  = fmaxf(c.x, c.y);
    float e0 = __expf(c.x - m), e1 = __expf(c.y - m);
    float inv = 1.f / (e0 + e1);
    p[b] = make_float2(e0 * inv, e1 * inv);
  }
}

extern "C" void kernel_launch(void* const* d_in, const int* in_sizes, int n_in,
                              void* d_out, int out_size, void* d_ws, size_t ws_size,
                              hipStream_t stream) {
  const float* U = (const float*)d_in[0];   // [1024, 2336, 4] fp32
  const float* W = (const float*)d_in[1];   // [2, 2336, 4, 16] fp32
  float* Out = (float*)d_out;               // [1024, 2] fp32
  caps_route<<<dim3(NBLK), dim3(NTH), 0, stream>>>(U, W, Out);
  caps_softmax<<<dim3(BATCH / 256), dim3(256), 0, stream>>>(Out);
}